// Round 8
// baseline (126.285 us; speedup 1.0000x reference)
//
#include <hip/hip_runtime.h>
#include <hip/hip_bf16.h>

// Problem constants (B=4, Tq=Tk=512, Q=K=1024, C=256)
#define M_ROWS 2048   // B*Tq = B*Tk
#define KDIM   1024
#define CDIM   256
#define TQ     512
#define TK     512

#define GBM 64        // m rows per block (gemm): 4 waves x 16
#define GBN 32        // c cols per block (gemm)
#define GBK 32        // k per iter

// 2*log2(e): tanh(x) = 1 - 2/(exp2(2log2e * x) + 1)
#define SCALE2LOG2E 2.8853900817779268f

typedef __attribute__((ext_vector_type(8))) short short8;
typedef __attribute__((ext_vector_type(8))) unsigned short ushort8;
typedef __attribute__((ext_vector_type(4))) float floatx4;
typedef __attribute__((ext_vector_type(2))) float f32x2;

__device__ __forceinline__ short2 cvt2(float x, float y) {
    __hip_bfloat162 h = __float22bfloat162_rn(make_float2(x, y));
    short2 r;
    __builtin_memcpy(&r, &h, sizeof(r));
    return r;
}
__device__ __forceinline__ unsigned short f2bf1(float x) {
    return (unsigned short)cvt2(x, x).x;
}
__device__ __forceinline__ float bf2f(unsigned short u) {
    return __builtin_bit_cast(float, (unsigned)u << 16);
}
__device__ __forceinline__ f32x2 splat2(float x) { return (f32x2){x, x}; }

// Transpose+convert: WT[c][k] bf16 <- W[k][c] f32.  (1024x256 -> 256x1024)
__global__ __launch_bounds__(256) void wt_kernel(
    const float* __restrict__ Wq, const float* __restrict__ Wk,
    unsigned short* __restrict__ WTq, unsigned short* __restrict__ WTk)
{
    __shared__ float tile[32][36];
    const float* W = blockIdx.z ? Wk : Wq;
    unsigned short* WT = blockIdx.z ? WTk : WTq;
    const int k0 = blockIdx.x * 32;
    const int c0 = blockIdx.y * 32;
    const int t  = threadIdx.x;
    const int row = t >> 3;          // 0..31
    const int col = (t & 7) * 4;     // 0,4,..,28

    float4 v = *(const float4*)&W[(size_t)(k0 + row) * CDIM + c0 + col];
    *(float4*)&tile[row][col] = v;
    __syncthreads();
    // thread t: c-row cr, k cols kc..kc+3
    const int cr = t >> 3;
    const int kc = (t & 7) * 4;
    short2 a = cvt2(tile[kc + 0][cr], tile[kc + 1][cr]);
    short2 b = cvt2(tile[kc + 2][cr], tile[kc + 3][cr]);
    short4 o = make_short4(a.x, a.y, b.x, b.y);
    *(short4*)&WT[(size_t)(c0 + cr) * KDIM + k0 + kc] = o;
}

// Barrier-free MFMA GEMM: E_bf16[c][m] = bf16(exp2(S * sum_k A[m][k]*W[k][c])),
// q-side prescaled by s_c = -0.5/w_c.
// NO LDS, NO __syncthreads: both MFMA operands loaded directly from global in
// fragment layout (A-op from WT[c][k] bf16 ushort8; B-op from A rows f32 + cvt).
// The VMEM queue is never force-drained -> fine-grained vmcnt waits only.
// Grid x = m-block so linear-id%8 = m%8: all 8 c-tiles of an A strip share an
// XCD -> A re-reads are L2-local.
__global__ __launch_bounds__(256) void gemm_mfma_kernel(
    const float* __restrict__ Aq, const float* __restrict__ Ak,
    const unsigned short* __restrict__ WTq, const unsigned short* __restrict__ WTk,
    const float* __restrict__ w_attn,
    unsigned short* __restrict__ Eq, unsigned short* __restrict__ Ek)
{
    const int z = blockIdx.z;
    const float* A = z ? Ak : Aq;
    const unsigned short* WT = z ? WTk : WTq;
    unsigned short* E = z ? Ek : Eq;

    const int t    = threadIdx.x;
    const int lane = t & 63;
    const int wave = t >> 6;
    const int m0   = blockIdx.x * GBM;
    const int n0   = blockIdx.y * GBN;
    const int li   = lane & 15;
    const int qd   = lane >> 4;

    const int row = m0 + wave * 16 + li;              // this lane's m row
    const float* Arow          = A  + (size_t)row * KDIM + qd * 8;
    const unsigned short* Wrow0 = WT + (size_t)(n0 + li) * KDIM + qd * 8;
    const unsigned short* Wrow1 = WT + (size_t)(n0 + 16 + li) * KDIM + qd * 8;

    floatx4 acc0 = {0.f, 0.f, 0.f, 0.f};   // c = n0 + qd*4 + r
    floatx4 acc1 = {0.f, 0.f, 0.f, 0.f};   // c + 16

    #pragma unroll 4
    for (int k0 = 0; k0 < KDIM; k0 += GBK) {
        float4 a0 = *(const float4*)&Arow[k0];
        float4 a1 = *(const float4*)&Arow[k0 + 4];
        short8 af0 = *(const short8*)&Wrow0[k0];
        short8 af1 = *(const short8*)&Wrow1[k0];
        short2 p0 = cvt2(a0.x, a0.y), p1 = cvt2(a0.z, a0.w);
        short2 p2 = cvt2(a1.x, a1.y), p3 = cvt2(a1.z, a1.w);
        short8 bv = { p0.x, p0.y, p1.x, p1.y, p2.x, p2.y, p3.x, p3.y };
        acc0 = __builtin_amdgcn_mfma_f32_16x16x32_bf16(af0, bv, acc0, 0, 0, 0);
        acc1 = __builtin_amdgcn_mfma_f32_16x16x32_bf16(af1, bv, acc1, 0, 0, 0);
    }

    #pragma unroll
    for (int r = 0; r < 4; ++r) {
        const int c0 = n0 + qd * 4 + r;
        const int c1 = c0 + 16;
        float s0 = z ? 1.0f : (-0.5f / w_attn[c0]);
        float s1 = z ? 1.0f : (-0.5f / w_attn[c1]);
        float v0 = __builtin_amdgcn_exp2f(acc0[r] * SCALE2LOG2E) * s0;
        float v1 = __builtin_amdgcn_exp2f(acc1[r] * SCALE2LOG2E) * s1;
        E[(size_t)c0 * M_ROWS + row] = f2bf1(v0);
        E[(size_t)c1 * M_ROWS + row] = f2bf1(v1);
    }
}

// scores[b][q][k] = (b_attn + sum_c w_c) + sum_c rcp(f_c),
//   f_c = fma(Eqs[c][q], Ek[c][k], s_c),  Eqs = s_c*e^{2 q2ctx}, Ek = e^{2 k2ctx}
// 4-way pairing: 1/f1+1/f2+1/f3+1/f4 = ((f1+f2)f3f4+(f3+f4)f1f2)*rcp(f1f2f3f4).
// E is bf16 in global (halved fetch), converted to fp32 during LDS staging.
__global__ __launch_bounds__(256) void bahdanau_kernel(
    const unsigned short* __restrict__ Eqs, const unsigned short* __restrict__ Ek,
    const float* __restrict__ w_attn, const float* __restrict__ b_attn,
    float* __restrict__ out)
{
    __shared__ float qs[64][36];          // [c][q] stride 36
    __shared__ float ks[64][36];          // [c][k]
    __shared__ __align__(16) float sl[CDIM];  // s_c = -0.5/w_c
    __shared__ float partial[4];          // per-wave w sums

    const int t  = threadIdx.x;
    const int b  = blockIdx.z;
    const int q0 = blockIdx.x * 32;
    const int k0 = blockIdx.y * 32;
    const int gq = b * TQ + q0;
    const int gk = b * TK + k0;
    const int tq = (t >> 4) * 2;      // q base (broadcast LDS reads)
    const int tk = (t & 15) * 2;      // k base (lanes -> consecutive k)

    const int lr = t >> 2;            // stage c-row 0..63
    const int lc = (t & 3) * 8;       // stage col*8

    {   // prologue: s_c and sum(w); CDIM == blockDim.x == 256
        float wv = w_attn[t];
        sl[t] = -0.5f / wv;
        float sum = wv;
        #pragma unroll
        for (int o = 32; o >= 1; o >>= 1) sum += __shfl_down(sum, o);
        if ((t & 63) == 0) partial[t >> 6] = sum;
    }

    // prefetch chunk 0 (16B = 8 bf16 per side per thread)
    ushort8 qu = *(const ushort8*)&Eqs[(size_t)lr * M_ROWS + gq + lc];
    ushort8 ku = *(const ushort8*)&Ek [(size_t)lr * M_ROWS + gk + lc];

    f32x2 accA = {0.f, 0.f};          // q row tq,   k pair
    f32x2 accB = {0.f, 0.f};          // q row tq+1, k pair

    for (int ch = 0; ch < 4; ++ch) {
        __syncthreads();              // previous chunk's compute done
        *(float4*)&qs[lr][lc]     = make_float4(bf2f(qu[0]), bf2f(qu[1]), bf2f(qu[2]), bf2f(qu[3]));
        *(float4*)&qs[lr][lc + 4] = make_float4(bf2f(qu[4]), bf2f(qu[5]), bf2f(qu[6]), bf2f(qu[7]));
        *(float4*)&ks[lr][lc]     = make_float4(bf2f(ku[0]), bf2f(ku[1]), bf2f(ku[2]), bf2f(ku[3]));
        *(float4*)&ks[lr][lc + 4] = make_float4(bf2f(ku[4]), bf2f(ku[5]), bf2f(ku[6]), bf2f(ku[7]));
        __syncthreads();
        if (ch < 3) {                 // prefetch next chunk
            const int c1 = (ch + 1) * 64;
            qu = *(const ushort8*)&Eqs[(size_t)(c1 + lr) * M_ROWS + gq + lc];
            ku = *(const ushort8*)&Ek [(size_t)(c1 + lr) * M_ROWS + gk + lc];
        }
        const int cb = ch * 64;
        #pragma unroll
        for (int cc = 0; cc < 64; cc += 4) {
            float4 s4 = *(const float4*)&sl[cb + cc];
            f32x2 q1 = *(const f32x2*)&qs[cc + 0][tq];
            f32x2 q2 = *(const f32x2*)&qs[cc + 1][tq];
            f32x2 q3 = *(const f32x2*)&qs[cc + 2][tq];
            f32x2 q4 = *(const f32x2*)&qs[cc + 3][tq];
            f32x2 k1 = *(const f32x2*)&ks[cc + 0][tk];
            f32x2 k2 = *(const f32x2*)&ks[cc + 1][tk];
            f32x2 k3 = *(const f32x2*)&ks[cc + 2][tk];
            f32x2 k4 = *(const f32x2*)&ks[cc + 3][tk];
            {   // group A: q component .x
                f32x2 f1 = __builtin_elementwise_fma(splat2(q1.x), k1, splat2(s4.x));
                f32x2 f2 = __builtin_elementwise_fma(splat2(q2.x), k2, splat2(s4.y));
                f32x2 f3 = __builtin_elementwise_fma(splat2(q3.x), k3, splat2(s4.z));
                f32x2 f4 = __builtin_elementwise_fma(splat2(q4.x), k4, splat2(s4.w));
                f32x2 p12 = f1 * f2, p34 = f3 * f4;
                f32x2 s12 = f1 + f2, s34 = f3 + f4;
                f32x2 num = __builtin_elementwise_fma(s12, p34, s34 * p12);
                f32x2 den = p12 * p34;
                f32x2 r = {__builtin_amdgcn_rcpf(den.x), __builtin_amdgcn_rcpf(den.y)};
                accA = __builtin_elementwise_fma(num, r, accA);
            }
            {   // group B: q component .y
                f32x2 f1 = __builtin_elementwise_fma(splat2(q1.y), k1, splat2(s4.x));
                f32x2 f2 = __builtin_elementwise_fma(splat2(q2.y), k2, splat2(s4.y));
                f32x2 f3 = __builtin_elementwise_fma(splat2(q3.y), k3, splat2(s4.z));
                f32x2 f4 = __builtin_elementwise_fma(splat2(q4.y), k4, splat2(s4.w));
                f32x2 p12 = f1 * f2, p34 = f3 * f4;
                f32x2 s12 = f1 + f2, s34 = f3 + f4;
                f32x2 num = __builtin_elementwise_fma(s12, p34, s34 * p12);
                f32x2 den = p12 * p34;
                f32x2 r = {__builtin_amdgcn_rcpf(den.x), __builtin_amdgcn_rcpf(den.y)};
                accB = __builtin_elementwise_fma(num, r, accB);
            }
        }
    }

    const float bias2 = *b_attn + partial[0] + partial[1] + partial[2] + partial[3];
    float* o = out + ((size_t)b * TQ + q0 + tq) * TK + k0 + tk;
    *(float2*)&o[0]  = make_float2(accA.x + bias2, accA.y + bias2);
    *(float2*)&o[TK] = make_float2(accB.x + bias2, accB.y + bias2);
}

extern "C" void kernel_launch(void* const* d_in, const int* in_sizes, int n_in,
                              void* d_out, int out_size, void* d_ws, size_t ws_size,
                              hipStream_t stream) {
    const float* query  = (const float*)d_in[0];
    const float* key    = (const float*)d_in[1];
    const float* Wq     = (const float*)d_in[2];
    const float* Wk     = (const float*)d_in[3];
    const float* w_attn = (const float*)d_in[4];
    const float* b_attn = (const float*)d_in[5];
    float* out = (float*)d_out;

    unsigned short* Eqs = (unsigned short*)d_ws;        // 256x2048 bf16 = 1 MB
    unsigned short* Ek  = Eqs + (size_t)CDIM * M_ROWS;  // 1 MB
    unsigned short* WTq = Ek  + (size_t)CDIM * M_ROWS;  // 256x1024 bf16 = 512 KB
    unsigned short* WTk = WTq + (size_t)CDIM * KDIM;    // 512 KB

    dim3 wt_grid(KDIM / 32, CDIM / 32, 2);         // 32 x 8 x 2
    wt_kernel<<<wt_grid, 256, 0, stream>>>(Wq, Wk, WTq, WTk);

    dim3 gemm_grid(M_ROWS / GBM, CDIM / GBN, 2);   // 32 x 8 x 2 = 512 blocks
    gemm_mfma_kernel<<<gemm_grid, 256, 0, stream>>>(query, key, WTq, WTk, w_attn, Eqs, Ek);

    dim3 main_grid(TQ / 32, TK / 32, 4);           // 16 x 16 x 4 = 1024 blocks
    bahdanau_kernel<<<main_grid, 256, 0, stream>>>(Eqs, Ek, w_attn, b_attn, out);
}

// Round 9
// 112.370 us; speedup vs baseline: 1.1238x; 1.1238x over previous
//
#include <hip/hip_runtime.h>
#include <hip/hip_bf16.h>

// Problem constants (B=4, Tq=Tk=512, Q=K=1024, C=256)
#define M_ROWS 2048   // B*Tq = B*Tk
#define KDIM   1024
#define CDIM   256
#define TQ     512
#define TK     512

#define GBM 64        // m rows per block (gemm): 4 waves x 16
#define GBN 32        // c cols per block (gemm)
#define CK  128       // k chunk per barrier-pair (8 chunks total)

// 2*log2(e): tanh(x) = 1 - 2/(exp2(2log2e * x) + 1)
#define SCALE2LOG2E 2.8853900817779268f

typedef __attribute__((ext_vector_type(8))) short short8;
typedef __attribute__((ext_vector_type(8))) unsigned short ushort8;
typedef __attribute__((ext_vector_type(4))) float floatx4;
typedef __attribute__((ext_vector_type(2))) float f32x2;

__device__ __forceinline__ short2 cvt2(float x, float y) {
    __hip_bfloat162 h = __float22bfloat162_rn(make_float2(x, y));
    short2 r;
    __builtin_memcpy(&r, &h, sizeof(r));
    return r;
}
__device__ __forceinline__ unsigned short f2bf1(float x) {
    return (unsigned short)cvt2(x, x).x;
}
__device__ __forceinline__ float bf2f(unsigned short u) {
    return __builtin_bit_cast(float, (unsigned)u << 16);
}
__device__ __forceinline__ f32x2 splat2(float x) { return (f32x2){x, x}; }

// MFMA GEMM: E_bf16[c][m] = bf16(exp2(S * sum_k A[m][k]*W[k][c])),
// q-side prescaled by s_c = -0.5/w_c.
// K chunked by 128: one barrier-pair per 128 k (8 total, vs 32 in R7) -> the
// vmcnt(0) drain at __syncthreads happens 4x less often, and within a chunk
// the 8 A fragment loads pipeline freely behind fine-grained vmcnt.
// W (shared by all 4 waves) staged in LDS as bf16 [c][k]; W f32 for chunk i+1
// register-prefetched right after the stage barrier (full compute phase to land).
// A-op frag: Ws[c=li][k-contig]; B-op frag: A row direct from global (per-lane
// float4 pair + packed cvt). Grid x=m-strip: blocks sharing an A strip have
// ids == bx mod 8 -> same XCD -> A re-reads (8 n-blocks) are L2-local.
__global__ __launch_bounds__(256) void gemm_mfma_kernel(
    const float* __restrict__ Aq, const float* __restrict__ Ak,
    const float* __restrict__ Wq, const float* __restrict__ Wk,
    const float* __restrict__ w_attn,
    unsigned short* __restrict__ Eq, unsigned short* __restrict__ Ek)
{
    __shared__ short Ws[GBN][CK + 8];   // [c][k] pad->136 shorts (stride 68 dw: frag reads 2-way=free)

    const int z = blockIdx.z;
    const float* A = z ? Ak : Aq;
    const float* W = z ? Wk : Wq;
    unsigned short* E = z ? Ek : Eq;

    const int t    = threadIdx.x;
    const int lane = t & 63;
    const int wave = t >> 6;
    const int m0   = blockIdx.x * GBM;
    const int n0   = blockIdx.y * GBN;
    const int li   = lane & 15;
    const int qd   = lane >> 4;

    const int row = m0 + wave * 16 + li;          // this lane's m row
    const float* Arow = A + (size_t)row * KDIM + qd * 8;

    // W staging role: thread t covers k-row kr (0..127), c half h (16 c's)
    const int kr = t >> 1;
    const int h  = t & 1;
    const float* Wst = W + (size_t)kr * CDIM + n0 + h * 16;   // + 4u + chunk*128*CDIM

    floatx4 acc0 = {0.f, 0.f, 0.f, 0.f};   // c = n0 + qd*4 + r
    floatx4 acc1 = {0.f, 0.f, 0.f, 0.f};   // c + 16

    // preload W f32 for chunk 0
    float4 wreg[4];
    #pragma unroll
    for (int u = 0; u < 4; ++u) wreg[u] = *(const float4*)&Wst[4 * u];

    for (int ck = 0; ck < KDIM / CK; ++ck) {
        __syncthreads();                         // prev chunk frag reads done
        #pragma unroll
        for (int u = 0; u < 4; ++u) {            // stage 16 bf16 into column kr
            short2 e0 = cvt2(wreg[u].x, wreg[u].y);
            short2 e1 = cvt2(wreg[u].z, wreg[u].w);
            const int c = h * 16 + 4 * u;
            Ws[c + 0][kr] = e0.x;
            Ws[c + 1][kr] = e0.y;
            Ws[c + 2][kr] = e1.x;
            Ws[c + 3][kr] = e1.y;
        }
        __syncthreads();                         // Ws ready
        if (ck + 1 < KDIM / CK) {                // prefetch next chunk's W f32
            const float* Wn = Wst + (size_t)(ck + 1) * CK * CDIM;
            #pragma unroll
            for (int u = 0; u < 4; ++u) wreg[u] = *(const float4*)&Wn[4 * u];
        }
        // compute: 4 k-steps, no barriers -> A loads pipeline via vmcnt
        #pragma unroll
        for (int s = 0; s < 4; ++s) {
            const int kk = ck * CK + s * 32;
            float4 a0 = *(const float4*)&Arow[kk];
            float4 a1 = *(const float4*)&Arow[kk + 4];
            short8 af0 = *(const short8*)&Ws[li][s * 32 + qd * 8];
            short8 af1 = *(const short8*)&Ws[16 + li][s * 32 + qd * 8];
            short2 p0 = cvt2(a0.x, a0.y), p1 = cvt2(a0.z, a0.w);
            short2 p2 = cvt2(a1.x, a1.y), p3 = cvt2(a1.z, a1.w);
            short8 bv = { p0.x, p0.y, p1.x, p1.y, p2.x, p2.y, p3.x, p3.y };
            acc0 = __builtin_amdgcn_mfma_f32_16x16x32_bf16(af0, bv, acc0, 0, 0, 0);
            acc1 = __builtin_amdgcn_mfma_f32_16x16x32_bf16(af1, bv, acc1, 0, 0, 0);
        }
    }

    #pragma unroll
    for (int r = 0; r < 4; ++r) {
        const int c0 = n0 + qd * 4 + r;
        const int c1 = c0 + 16;
        float s0 = z ? 1.0f : (-0.5f / w_attn[c0]);
        float s1 = z ? 1.0f : (-0.5f / w_attn[c1]);
        float v0 = __builtin_amdgcn_exp2f(acc0[r] * SCALE2LOG2E) * s0;
        float v1 = __builtin_amdgcn_exp2f(acc1[r] * SCALE2LOG2E) * s1;
        E[(size_t)c0 * M_ROWS + row] = f2bf1(v0);
        E[(size_t)c1 * M_ROWS + row] = f2bf1(v1);
    }
}

// scores[b][q][k] = (b_attn + sum_c w_c) + sum_c rcp(f_c),
//   f_c = fma(Eqs[c][q], Ek[c][k], s_c),  Eqs = s_c*e^{2 q2ctx}, Ek = e^{2 k2ctx}
// 4-way pairing: 1/f1+1/f2+1/f3+1/f4 = ((f1+f2)f3f4+(f3+f4)f1f2)*rcp(f1f2f3f4).
// E is bf16 in global (halved fetch), converted to fp32 during LDS staging.
__global__ __launch_bounds__(256) void bahdanau_kernel(
    const unsigned short* __restrict__ Eqs, const unsigned short* __restrict__ Ek,
    const float* __restrict__ w_attn, const float* __restrict__ b_attn,
    float* __restrict__ out)
{
    __shared__ float qs[64][36];          // [c][q] stride 36
    __shared__ float ks[64][36];          // [c][k]
    __shared__ __align__(16) float sl[CDIM];  // s_c = -0.5/w_c
    __shared__ float partial[4];          // per-wave w sums

    const int t  = threadIdx.x;
    const int b  = blockIdx.z;
    const int q0 = blockIdx.x * 32;
    const int k0 = blockIdx.y * 32;
    const int gq = b * TQ + q0;
    const int gk = b * TK + k0;
    const int tq = (t >> 4) * 2;      // q base (broadcast LDS reads)
    const int tk = (t & 15) * 2;      // k base (lanes -> consecutive k)

    const int lr = t >> 2;            // stage c-row 0..63
    const int lc = (t & 3) * 8;       // stage col*8

    {   // prologue: s_c and sum(w); CDIM == blockDim.x == 256
        float wv = w_attn[t];
        sl[t] = -0.5f / wv;
        float sum = wv;
        #pragma unroll
        for (int o = 32; o >= 1; o >>= 1) sum += __shfl_down(sum, o);
        if ((t & 63) == 0) partial[t >> 6] = sum;
    }

    // prefetch chunk 0 (16B = 8 bf16 per side per thread)
    ushort8 qu = *(const ushort8*)&Eqs[(size_t)lr * M_ROWS + gq + lc];
    ushort8 ku = *(const ushort8*)&Ek [(size_t)lr * M_ROWS + gk + lc];

    f32x2 accA = {0.f, 0.f};          // q row tq,   k pair
    f32x2 accB = {0.f, 0.f};          // q row tq+1, k pair

    for (int ch = 0; ch < 4; ++ch) {
        __syncthreads();              // previous chunk's compute done
        *(float4*)&qs[lr][lc]     = make_float4(bf2f(qu[0]), bf2f(qu[1]), bf2f(qu[2]), bf2f(qu[3]));
        *(float4*)&qs[lr][lc + 4] = make_float4(bf2f(qu[4]), bf2f(qu[5]), bf2f(qu[6]), bf2f(qu[7]));
        *(float4*)&ks[lr][lc]     = make_float4(bf2f(ku[0]), bf2f(ku[1]), bf2f(ku[2]), bf2f(ku[3]));
        *(float4*)&ks[lr][lc + 4] = make_float4(bf2f(ku[4]), bf2f(ku[5]), bf2f(ku[6]), bf2f(ku[7]));
        __syncthreads();
        if (ch < 3) {                 // prefetch next chunk
            const int c1 = (ch + 1) * 64;
            qu = *(const ushort8*)&Eqs[(size_t)(c1 + lr) * M_ROWS + gq + lc];
            ku = *(const ushort8*)&Ek [(size_t)(c1 + lr) * M_ROWS + gk + lc];
        }
        const int cb = ch * 64;
        #pragma unroll
        for (int cc = 0; cc < 64; cc += 4) {
            float4 s4 = *(const float4*)&sl[cb + cc];
            f32x2 q1 = *(const f32x2*)&qs[cc + 0][tq];
            f32x2 q2 = *(const f32x2*)&qs[cc + 1][tq];
            f32x2 q3 = *(const f32x2*)&qs[cc + 2][tq];
            f32x2 q4 = *(const f32x2*)&qs[cc + 3][tq];
            f32x2 k1 = *(const f32x2*)&ks[cc + 0][tk];
            f32x2 k2 = *(const f32x2*)&ks[cc + 1][tk];
            f32x2 k3 = *(const f32x2*)&ks[cc + 2][tk];
            f32x2 k4 = *(const f32x2*)&ks[cc + 3][tk];
            {   // group A: q component .x
                f32x2 f1 = __builtin_elementwise_fma(splat2(q1.x), k1, splat2(s4.x));
                f32x2 f2 = __builtin_elementwise_fma(splat2(q2.x), k2, splat2(s4.y));
                f32x2 f3 = __builtin_elementwise_fma(splat2(q3.x), k3, splat2(s4.z));
                f32x2 f4 = __builtin_elementwise_fma(splat2(q4.x), k4, splat2(s4.w));
                f32x2 p12 = f1 * f2, p34 = f3 * f4;
                f32x2 s12 = f1 + f2, s34 = f3 + f4;
                f32x2 num = __builtin_elementwise_fma(s12, p34, s34 * p12);
                f32x2 den = p12 * p34;
                f32x2 r = {__builtin_amdgcn_rcpf(den.x), __builtin_amdgcn_rcpf(den.y)};
                accA = __builtin_elementwise_fma(num, r, accA);
            }
            {   // group B: q component .y
                f32x2 f1 = __builtin_elementwise_fma(splat2(q1.y), k1, splat2(s4.x));
                f32x2 f2 = __builtin_elementwise_fma(splat2(q2.y), k2, splat2(s4.y));
                f32x2 f3 = __builtin_elementwise_fma(splat2(q3.y), k3, splat2(s4.z));
                f32x2 f4 = __builtin_elementwise_fma(splat2(q4.y), k4, splat2(s4.w));
                f32x2 p12 = f1 * f2, p34 = f3 * f4;
                f32x2 s12 = f1 + f2, s34 = f3 + f4;
                f32x2 num = __builtin_elementwise_fma(s12, p34, s34 * p12);
                f32x2 den = p12 * p34;
                f32x2 r = {__builtin_amdgcn_rcpf(den.x), __builtin_amdgcn_rcpf(den.y)};
                accB = __builtin_elementwise_fma(num, r, accB);
            }
        }
    }

    const float bias2 = *b_attn + partial[0] + partial[1] + partial[2] + partial[3];
    float* o = out + ((size_t)b * TQ + q0 + tq) * TK + k0 + tk;
    *(float2*)&o[0]  = make_float2(accA.x + bias2, accA.y + bias2);
    *(float2*)&o[TK] = make_float2(accB.x + bias2, accB.y + bias2);
}

extern "C" void kernel_launch(void* const* d_in, const int* in_sizes, int n_in,
                              void* d_out, int out_size, void* d_ws, size_t ws_size,
                              hipStream_t stream) {
    const float* query  = (const float*)d_in[0];
    const float* key    = (const float*)d_in[1];
    const float* Wq     = (const float*)d_in[2];
    const float* Wk     = (const float*)d_in[3];
    const float* w_attn = (const float*)d_in[4];
    const float* b_attn = (const float*)d_in[5];
    float* out = (float*)d_out;

    unsigned short* Eqs = (unsigned short*)d_ws;        // 256x2048 bf16 = 1 MB
    unsigned short* Ek  = Eqs + (size_t)CDIM * M_ROWS;  // 1 MB

    dim3 gemm_grid(M_ROWS / GBM, CDIM / GBN, 2);   // 32 x 8 x 2 = 512 blocks
    gemm_mfma_kernel<<<gemm_grid, 256, 0, stream>>>(query, key, Wq, Wk, w_attn, Eqs, Ek);

    dim3 main_grid(TQ / 32, TK / 32, 4);           // 16 x 16 x 4 = 1024 blocks
    bahdanau_kernel<<<main_grid, 256, 0, stream>>>(Eqs, Ek, w_attn, b_attn, out);
}